// Round 5
// baseline (4183.492 us; speedup 1.0000x reference)
//
#include <hip/hip_runtime.h>
#include <cstdint>
#include <cstddef>

typedef unsigned short u16;
typedef __bf16 bf16_t;
typedef bf16_t bf16x8 __attribute__((ext_vector_type(8)));
typedef float f32x4 __attribute__((ext_vector_type(4)));

static constexpr int HID    = 512;
static constexpr int BATCH  = 1024;
static constexpr int NSTEPS = 95;   // T + future - 1 = 64 + 31
static constexpr int T_OBS  = 64;
static constexpr int OUTW   = 190;  // 2 * NSTEPS

// ---------- helpers ----------
__device__ __forceinline__ u16 f2bf(float x) {
  union { float f; uint32_t u; } c; c.f = x;
  uint32_t r = c.u + 0x7fffu + ((c.u >> 16) & 1u);   // RNE
  return (u16)(r >> 16);
}
__device__ __forceinline__ float bf2f(u16 h) {
  union { uint32_t u; float f; } c; c.u = ((uint32_t)h) << 16;
  return c.f;
}
__device__ __forceinline__ float sigm(float x) { return 1.f / (1.f + __expf(-x)); }
__device__ __forceinline__ float tanh_fast(float x) {
  float ax = fabsf(x);
  float t  = __expf(-2.f * ax);
  float r  = (1.f - t) / (1.f + t);
  return x < 0.f ? -r : r;
}

// ---------- weight prep (gate-interleaved column order) ----------
// col n = 4*h + g  <->  original row r = g*512 + h
__global__ void prep_bt1(const float* __restrict__ Whh1, u16* __restrict__ Bt1) {
  int idx = blockIdx.x * 256 + threadIdx.x;       // 2048*1024
  int n = idx >> 10, kk = idx & 1023;
  int r = (n & 3) * HID + (n >> 2);
  int k = kk & 511;
  float v = Whh1[r * HID + k];
  u16 hi = f2bf(v);
  Bt1[idx] = (kk < 512) ? hi : f2bf(v - bf2f(hi));
}
__global__ void prep_bt2(const float* __restrict__ Wih2, const float* __restrict__ Whh2,
                         u16* __restrict__ Bt2) {
  int idx = blockIdx.x * 256 + threadIdx.x;       // 2048*2048
  int n = idx >> 11, kk = idx & 2047;
  int r = (n & 3) * HID + (n >> 2);
  int k = kk & 1023;
  float v = (k < 512) ? Wih2[r * HID + k] : Whh2[r * HID + (k - 512)];
  u16 hi = f2bf(v);
  Bt2[idx] = (kk < 1024) ? hi : f2bf(v - bf2f(hi));
}
__global__ void prep_small(const float* __restrict__ b1, const float* __restrict__ b2,
                           const float* __restrict__ Wih1,
                           float* __restrict__ b1p, float* __restrict__ b2p,
                           float* __restrict__ w1p) {
  int n = blockIdx.x * 256 + threadIdx.x;
  if (n >= 2048) return;
  int r = (n & 3) * HID + (n >> 2);
  b1p[n] = b1[r];
  b2p[n] = b2[r];
  w1p[2 * n + 0] = Wih1[2 * r + 0];
  w1p[2 * n + 1] = Wih1[2 * r + 1];
}
__global__ void init_out(const float* __restrict__ bl, float* __restrict__ out) {
  int i = blockIdx.x * 256 + threadIdx.x;
  if (i < BATCH * OUTW) out[i] = bl[i & 1];
}

// ---------- fused gate-GEMM + LSTM cell (+ optional out-projection) ----------
struct GArgs {
  const u16* Ah0; const u16* Ah1;   // hi activation chunks ([1024][512] each)
  const u16* Al0; const u16* Al1;   // lo activation chunks
  const u16* Bt;  int bstride;      // bf16 weight panel
  const float* bias;                // reordered bias [2048]
  const float* xptr; int xstride;   // layer-1 input (2 floats/row)
  const float* wih;                 // reordered Wih1 [2048][2]
  float* CstT;                      // cell state TRANSPOSED [512][1024], RMW
  u16* Hh; u16* Hl;                 // output h hi/lo [1024][512]
  const float* wl;                  // Wl [2][512] original order
  float* oacc;                      // out + 2t (atomic accumulate)
};

// Load one BK=128 K-step into 8 NAMED uint4 scalars (R2/R3 lesson: no arrays).
#define LOADT(ks)                                                              \
  {                                                                            \
    const int c_ = (ks) >> 2, k0_ = ((ks) & 3) * 128;                          \
    const u16* Ab_; int boff_;                                                 \
    if (NCH == 3) {  /* chunks {Ah0, Ah0, Al0} x B {hi, lo, hi} */             \
      Ab_ = (c_ < 2) ? Ah0 : Al0;                                              \
      boff_ = (c_ == 1) ? 512 : 0;                                             \
    } else {         /* {Ah0,Ah1,Ah0,Ah1,Al0,Al1} x B {hi,hi,lo,lo,hi,hi} */   \
      const u16* Abh_ = (c_ & 1) ? Ah1 : Ah0;                                  \
      const u16* Abl_ = (c_ & 1) ? Al1 : Al0;                                  \
      Ab_ = (c_ < 4) ? Abh_ : Abl_;                                            \
      boff_ = (c_ < 4) ? c_ * 512 : (c_ - 4) * 512;                            \
    }                                                                          \
    const u16* Ap_ = Ab_ + (size_t)(mt * 64) * HID + k0_ + sl * 8;             \
    const u16* Bp_ = Bt + (size_t)(nt * 64) * bstride + boff_ + k0_ + sl * 8;  \
    pa0 = *(const uint4*)(Ap_ + (size_t)(r0 +  0) * HID);                      \
    pa1 = *(const uint4*)(Ap_ + (size_t)(r0 + 16) * HID);                      \
    pa2 = *(const uint4*)(Ap_ + (size_t)(r0 + 32) * HID);                      \
    pa3 = *(const uint4*)(Ap_ + (size_t)(r0 + 48) * HID);                      \
    pb0 = *(const uint4*)(Bp_ + (size_t)(r0 +  0) * bstride);                  \
    pb1 = *(const uint4*)(Bp_ + (size_t)(r0 + 16) * bstride);                  \
    pb2 = *(const uint4*)(Bp_ + (size_t)(r0 + 32) * bstride);                  \
    pb3 = *(const uint4*)(Bp_ + (size_t)(r0 + 48) * bstride);                  \
  }

// BM=BN=64, BK=128. LDS: As[64][128] + Bs[64][128] bf16 = 32768 B, XOR-16 swizzled.
// MFMA operands SWAPPED: D[n][m] = W x H^T  -> each lane holds a full i/f/g/o
// gate quad in one f32x4 -> fully in-register epilogue (no C LDS round-trip).
template <int NCH, bool HASX, bool PROJ>
__device__ __forceinline__ void run_gemm(const GArgs& g, int mt, int nt, char* smem) {
  const u16* const Ah0 = g.Ah0;  const u16* const Ah1 = g.Ah1;
  const u16* const Al0 = g.Al0;  const u16* const Al1 = g.Al1;
  const u16* const Bt  = g.Bt;   const int bstride = g.bstride;
  const float* const bias = g.bias;
  const float* const xptr = g.xptr; const int xstride = g.xstride;
  const float* const wih  = g.wih;
  float* const CstT = g.CstT;
  u16* const Hh = g.Hh;  u16* const Hl = g.Hl;
  const float* const wl = g.wl;
  float* const oacc = g.oacc;

  u16* As = (u16*)smem;                  // H tile  [64 rows(m)][128 k] swizzled
  u16* Bs = (u16*)(smem + 16384);        // W tile  [64 rows(n)][128 k] swizzled

  const int tid = threadIdx.x;
  const int wid = tid >> 6, lane = tid & 63;
  const int wq = wid >> 1, wp = wid & 1;   // wq: gate(n)-half, wp: batch(m)-half
  const int r0 = tid >> 4;                 // 0..15  (staging row group)
  const int sl = tid & 15;                 // 16B slot
  const int wcol = ((sl ^ r0) & 15) << 4;  // swizzled write byte-col (const/thread)

  const int l15 = lane & 15, lq = lane >> 4;
  const int ea = ((lq ^ l15) << 3);        // swizzled read offset (u16 units)
  const int hrow0 = wp * 32 + l15, hrow1 = hrow0 + 16;   // H rows (m)
  const int wrow0 = wq * 32 + l15, wrow1 = wrow0 + 16;   // W rows (n)

  f32x4 acc00 = {}, acc01 = {}, acc10 = {}, acc11 = {};
  constexpr int TOT = NCH * 4;       // K-steps of 128

  uint4 pa0, pa1, pa2, pa3, pb0, pb1, pb2, pb3;
  LOADT(0);

  for (int ks = 0; ks < TOT; ++ks) {
    __syncthreads();                 // prev compute done, LDS free
    *(uint4*)((char*)As + (r0 +  0) * 256 + wcol) = pa0;
    *(uint4*)((char*)As + (r0 + 16) * 256 + wcol) = pa1;
    *(uint4*)((char*)As + (r0 + 32) * 256 + wcol) = pa2;
    *(uint4*)((char*)As + (r0 + 48) * 256 + wcol) = pa3;
    *(uint4*)((char*)Bs + (r0 +  0) * 256 + wcol) = pb0;
    *(uint4*)((char*)Bs + (r0 + 16) * 256 + wcol) = pb1;
    *(uint4*)((char*)Bs + (r0 + 32) * 256 + wcol) = pb2;
    *(uint4*)((char*)Bs + (r0 + 48) * 256 + wcol) = pb3;
    __syncthreads();                 // LDS ready
    if (ks + 1 < TOT) LOADT(ks + 1); // prefetch hides under MFMA
#pragma unroll
    for (int kk = 0; kk < 4; ++kk) {
      const int eo = ea ^ (kk << 5);
      bf16x8 w0 = *(const bf16x8*)(Bs + wrow0 * 128 + eo);
      bf16x8 w1 = *(const bf16x8*)(Bs + wrow1 * 128 + eo);
      bf16x8 h0 = *(const bf16x8*)(As + hrow0 * 128 + eo);
      bf16x8 h1 = *(const bf16x8*)(As + hrow1 * 128 + eo);
      acc00 = __builtin_amdgcn_mfma_f32_16x16x32_bf16(w0, h0, acc00, 0, 0, 0);
      acc01 = __builtin_amdgcn_mfma_f32_16x16x32_bf16(w0, h1, acc01, 0, 0, 0);
      acc10 = __builtin_amdgcn_mfma_f32_16x16x32_bf16(w1, h0, acc10, 0, 0, 0);
      acc11 = __builtin_amdgcn_mfma_f32_16x16x32_bf16(w1, h1, acc11, 0, 0, 0);
    }
  }

  // ---- in-register epilogue ----
  __syncthreads();                   // all LDS reads done; reuse smem for H stage
  u16* Hsh = (u16*)smem;             // [64][17]
  u16* Hsl = Hsh + 64 * 17;          // [64][17]

  const int mg0 = mt * 64, hg0 = nt * 16;
  float s0a = 0.f, s1a = 0.f, s0b = 0.f, s1b = 0.f;

#pragma unroll
  for (int i = 0; i < 2; ++i)
#pragma unroll
    for (int j = 0; j < 2; ++j) {
      f32x4 ac = (i == 0) ? ((j == 0) ? acc00 : acc01)
                          : ((j == 0) ? acc10 : acc11);
      int hl = wq * 8 + i * 4 + lq;            // 0..15 within N-tile
      int hg = hg0 + hl;
      int ml = wp * 32 + j * 16 + l15;         // 0..63 within M-tile
      int mg = mg0 + ml;
      float4 b4 = *(const float4*)(bias + 4 * hg);
      float g0 = ac[0] + b4.x, g1 = ac[1] + b4.y;
      float g2 = ac[2] + b4.z, g3 = ac[3] + b4.w;
      if (HASX) {
        float x0 = xptr[(size_t)mg * xstride + 0];
        float x1 = xptr[(size_t)mg * xstride + 1];
        float4 wA = *(const float4*)(wih + 8 * hg);
        float4 wB = *(const float4*)(wih + 8 * hg + 4);
        g0 += x0 * wA.x + x1 * wA.y;  g1 += x0 * wA.z + x1 * wA.w;
        g2 += x0 * wB.x + x1 * wB.y;  g3 += x0 * wB.z + x1 * wB.w;
      }
      float ig = sigm(g0), fg = sigm(g1), gg = tanh_fast(g2), og = sigm(g3);
      float* cp = CstT + (size_t)hg * BATCH + mg;    // coalesced over l15
      float cn = fg * (*cp) + ig * gg;
      *cp = cn;
      float hn = og * tanh_fast(cn);
      u16 hi = f2bf(hn);
      Hsh[ml * 17 + hl] = hi;
      Hsl[ml * 17 + hl] = f2bf(hn - bf2f(hi));
      if (PROJ) {
        float p0 = hn * wl[hg], p1 = hn * wl[HID + hg];
        if (j == 0) { s0a += p0; s1a += p1; } else { s0b += p0; s1b += p1; }
      }
    }

  if (PROJ) {                        // sum this wave's 8 h-values per m-row
    s0a += __shfl_xor(s0a, 16); s0a += __shfl_xor(s0a, 32);
    s1a += __shfl_xor(s1a, 16); s1a += __shfl_xor(s1a, 32);
    s0b += __shfl_xor(s0b, 16); s0b += __shfl_xor(s0b, 32);
    s1b += __shfl_xor(s1b, 16); s1b += __shfl_xor(s1b, 32);
    if (lq == 0) {
      int mgA = mg0 + wp * 32 + l15;
      unsafeAtomicAdd(&oacc[(size_t)mgA * OUTW + 0], s0a);
      unsafeAtomicAdd(&oacc[(size_t)mgA * OUTW + 1], s1a);
      int mgB = mgA + 16;
      unsafeAtomicAdd(&oacc[(size_t)mgB * OUTW + 0], s0b);
      unsafeAtomicAdd(&oacc[(size_t)mgB * OUTW + 1], s1b);
    }
  }

  __syncthreads();                   // H stage complete
#pragma unroll
  for (int q = 0; q < 4; ++q) {      // coalesced H writeback (32B per 16 lanes)
    int m = (tid >> 4) + 16 * q, c = tid & 15;
    Hh[(size_t)(mg0 + m) * HID + hg0 + c] = Hsh[m * 17 + c];
    Hl[(size_t)(mg0 + m) * HID + hg0 + c] = Hsl[m * 17 + c];
  }
}

// XCD-pinned tile mapping: xcd = bid&7 always owns nt in [xcd*4, xcd*4+4)
template <int NCH, bool HASX, bool PROJ>
__global__ __launch_bounds__(256, 2) void step_single(GArgs ga) {
  __shared__ __align__(16) char smem[32768];
  int bid = blockIdx.x;
  int x = bid & 7, j = bid >> 3;     // j in [0,64)
  int nt = x * 4 + (j & 3);
  int mt = j >> 2;
  run_gemm<NCH, HASX, PROJ>(ga, mt, nt, smem);
}

// grid 1024: j<64 -> L2(t) (+proj), j>=64 -> L1(t+1)  (independent GEMMs)
__global__ __launch_bounds__(256, 2) void step_fused(GArgs g2, GArgs g1) {
  __shared__ __align__(16) char smem[32768];
  int bid = blockIdx.x;
  int x = bid & 7, j = bid >> 3;     // j in [0,128)
  int jj = j & 63;
  int nt = x * 4 + (jj & 3);
  int mt = jj >> 2;
  if (j < 64) run_gemm<6, false, true>(g2, mt, nt, smem);
  else        run_gemm<3, true, false>(g1, mt, nt, smem);
}

// ---------- host ----------
extern "C" void kernel_launch(void* const* d_in, const int* in_sizes, int n_in,
                              void* d_out, int out_size, void* d_ws, size_t ws_size,
                              hipStream_t stream) {
  const float* x    = (const float*)d_in[0];
  const float* Wih1 = (const float*)d_in[1];
  const float* Whh1 = (const float*)d_in[2];
  const float* b1   = (const float*)d_in[3];
  const float* Wih2 = (const float*)d_in[4];
  const float* Whh2 = (const float*)d_in[5];
  const float* b2   = (const float*)d_in[6];
  const float* Wl   = (const float*)d_in[7];
  const float* bl   = (const float*)d_in[8];
  float* out = (float*)d_out;
  (void)in_sizes; (void)n_in; (void)out_size; (void)ws_size;

  char* p = (char*)d_ws;
  auto alloc = [&](size_t bytes) -> char* {
    char* r = p; p += (bytes + 255) & ~(size_t)255; return r;
  };
  u16* Bt1 = (u16*)alloc((size_t)2048 * 1024 * 2);   // 4 MB
  u16* Bt2 = (u16*)alloc((size_t)2048 * 2048 * 2);   // 8 MB
  char* state0 = p;
  u16* Hb[8];                                        // H1h[2],H1l[2],H2h[2],H2l[2]
  for (int i = 0; i < 8; ++i) Hb[i] = (u16*)alloc((size_t)BATCH * HID * 2);
  float* C1 = (float*)alloc((size_t)BATCH * HID * 4);  // stored [512][1024]
  float* C2 = (float*)alloc((size_t)BATCH * HID * 4);
  size_t state_bytes = (size_t)(p - state0);
  float* b1p = (float*)alloc(2048 * 4);
  float* b2p = (float*)alloc(2048 * 4);
  float* w1p = (float*)alloc(2048 * 2 * 4);

  hipMemsetAsync(state0, 0, state_bytes, stream);    // h,c = 0
  init_out<<<(BATCH * OUTW + 255) / 256, 256, 0, stream>>>(bl, out);
  prep_bt1<<<8192, 256, 0, stream>>>(Whh1, Bt1);
  prep_bt2<<<16384, 256, 0, stream>>>(Wih2, Whh2, Bt2);
  prep_small<<<8, 256, 0, stream>>>(b1, b2, Wih1, b1p, b2p, w1p);

  auto mkL1 = [&](int t) -> GArgs {
    int par = t & 1, prev = par ^ 1;
    GArgs a{};
    a.Ah0 = Hb[0 + prev]; a.Ah1 = nullptr;
    a.Al0 = Hb[2 + prev]; a.Al1 = nullptr;
    a.Bt = Bt1; a.bstride = 1024; a.bias = b1p;
    a.xptr = (t < T_OBS) ? (x + 2 * t) : (out + 2 * (t - 1));
    a.xstride = (t < T_OBS) ? (2 * T_OBS) : OUTW;
    a.wih = w1p; a.CstT = C1;
    a.Hh = Hb[0 + par]; a.Hl = Hb[2 + par];
    a.wl = nullptr; a.oacc = nullptr;
    return a;
  };
  auto mkL2 = [&](int t) -> GArgs {
    int par = t & 1, prev = par ^ 1;
    GArgs a{};
    a.Ah0 = Hb[0 + par];  a.Ah1 = Hb[4 + prev];
    a.Al0 = Hb[2 + par];  a.Al1 = Hb[6 + prev];
    a.Bt = Bt2; a.bstride = 2048; a.bias = b2p;
    a.xptr = nullptr; a.xstride = 0; a.wih = nullptr;
    a.CstT = C2;
    a.Hh = Hb[4 + par]; a.Hl = Hb[6 + par];
    a.wl = Wl; a.oacc = out + 2 * t;
    return a;
  };

  // step 0 layer 1
  step_single<3, true, false><<<512, 256, 0, stream>>>(mkL1(0));
  // observed steps: L2(t) and L1(t+1) are independent -> one 1024-WG dispatch
  for (int t = 0; t < T_OBS - 1; ++t)
    step_fused<<<1024, 256, 0, stream>>>(mkL2(t), mkL1(t + 1));
  // last observed L2 (writes out[63])
  step_single<6, false, true><<<512, 256, 0, stream>>>(mkL2(T_OBS - 1));
  // future steps: strict chain L1 -> L2(+proj) -> L1 ...
  for (int t = T_OBS; t < NSTEPS; ++t) {
    step_single<3, true, false><<<512, 256, 0, stream>>>(mkL1(t));
    step_single<6, false, true><<<512, 256, 0, stream>>>(mkL2(t));
  }
}

// Round 6
// 3878.212 us; speedup vs baseline: 1.0787x; 1.0787x over previous
//
#include <hip/hip_runtime.h>
#include <cstdint>
#include <cstddef>

typedef unsigned short u16;
typedef __bf16 bf16_t;
typedef bf16_t bf16x8 __attribute__((ext_vector_type(8)));
typedef float f32x4 __attribute__((ext_vector_type(4)));

static constexpr int HID    = 512;
static constexpr int BATCH  = 1024;
static constexpr int NSTEPS = 95;   // T + future - 1 = 64 + 31
static constexpr int T_OBS  = 64;
static constexpr int OUTW   = 190;  // 2 * NSTEPS

// ---------- helpers ----------
__device__ __forceinline__ u16 f2bf(float x) {
  union { float f; uint32_t u; } c; c.f = x;
  uint32_t r = c.u + 0x7fffu + ((c.u >> 16) & 1u);   // RNE
  return (u16)(r >> 16);
}
__device__ __forceinline__ float bf2f(u16 h) {
  union { uint32_t u; float f; } c; c.u = ((uint32_t)h) << 16;
  return c.f;
}
__device__ __forceinline__ float sigm(float x) { return 1.f / (1.f + __expf(-x)); }
__device__ __forceinline__ float tanh_fast(float x) {
  float ax = fabsf(x);
  float t  = __expf(-2.f * ax);
  float r  = (1.f - t) / (1.f + t);
  return x < 0.f ? -r : r;
}

// ---------- weight prep (gate-interleaved column order) ----------
// col n = 4*h + g  <->  original row r = g*512 + h
__global__ void prep_bt1(const float* __restrict__ Whh1, u16* __restrict__ Bt1) {
  int idx = blockIdx.x * 256 + threadIdx.x;       // 2048*1024
  int n = idx >> 10, kk = idx & 1023;
  int r = (n & 3) * HID + (n >> 2);
  int k = kk & 511;
  float v = Whh1[r * HID + k];
  u16 hi = f2bf(v);
  Bt1[idx] = (kk < 512) ? hi : f2bf(v - bf2f(hi));
}
__global__ void prep_bt2(const float* __restrict__ Wih2, const float* __restrict__ Whh2,
                         u16* __restrict__ Bt2) {
  int idx = blockIdx.x * 256 + threadIdx.x;       // 2048*2048
  int n = idx >> 11, kk = idx & 2047;
  int r = (n & 3) * HID + (n >> 2);
  int k = kk & 1023;
  float v = (k < 512) ? Wih2[r * HID + k] : Whh2[r * HID + (k - 512)];
  u16 hi = f2bf(v);
  Bt2[idx] = (kk < 1024) ? hi : f2bf(v - bf2f(hi));
}
__global__ void prep_small(const float* __restrict__ b1, const float* __restrict__ b2,
                           const float* __restrict__ Wih1,
                           float* __restrict__ b1p, float* __restrict__ b2p,
                           float* __restrict__ w1p) {
  int n = blockIdx.x * 256 + threadIdx.x;
  if (n >= 2048) return;
  int r = (n & 3) * HID + (n >> 2);
  b1p[n] = b1[r];
  b2p[n] = b2[r];
  w1p[2 * n + 0] = Wih1[2 * r + 0];
  w1p[2 * n + 1] = Wih1[2 * r + 1];
}
__global__ void init_out(const float* __restrict__ bl, float* __restrict__ out) {
  int i = blockIdx.x * 256 + threadIdx.x;
  if (i < BATCH * OUTW) out[i] = bl[i & 1];
}

// ---------- fused gate-GEMM + LSTM cell (+ optional out-projection) ----------
struct GArgs {
  const u16* Ah0; const u16* Ah1;   // hi activation chunks ([1024][512] each)
  const u16* Al0; const u16* Al1;   // lo activation chunks
  const u16* Bt;                    // bf16 weight panel [2048][2*KTOT]
  const float* bias;                // reordered bias [2048]
  const float* xptr; int xstride;   // layer-1 input (2 floats/row)
  const float* wih;                 // reordered Wih1 [2048][2]
  float* CstT;                      // cell state TRANSPOSED [512][1024], RMW
  u16* Hh; u16* Hl;                 // output h hi/lo [1024][512]
  const float* wl;                  // Wl [2][512] original order
  float* oacc;                      // out + 2t (atomic accumulate)
};

// Load one BK=64 K-step (Ah,Al,Bh,Bl panels) into 12 NAMED uint4 scalars.
#define LOADT(ks)                                                               \
  {                                                                             \
    const int kA_ = ((ks) & 7) * 64;                                            \
    const int kB_ = (ks) * 64;                                                  \
    const u16* Ah_ = (KTOT == 1024 && (ks) >= 8) ? Ah1 : Ah0;                   \
    const u16* Al_ = (KTOT == 1024 && (ks) >= 8) ? Al1 : Al0;                   \
    const u16* ApH_ = Ah_ + (size_t)(mt * 128 + r0) * HID + kA_ + sl * 8;       \
    const u16* ApL_ = Al_ + (size_t)(mt * 128 + r0) * HID + kA_ + sl * 8;       \
    const u16* BpH_ = Bt + (size_t)(nt * 64 + r0) * (2 * KTOT) + kB_ + sl * 8;  \
    const u16* BpL_ = BpH_ + KTOT;                                              \
    pah0 = *(const uint4*)(ApH_ +  0 * HID);                                    \
    pah1 = *(const uint4*)(ApH_ + 32 * HID);                                    \
    pah2 = *(const uint4*)(ApH_ + 64 * HID);                                    \
    pah3 = *(const uint4*)(ApH_ + 96 * HID);                                    \
    pal0 = *(const uint4*)(ApL_ +  0 * HID);                                    \
    pal1 = *(const uint4*)(ApL_ + 32 * HID);                                    \
    pal2 = *(const uint4*)(ApL_ + 64 * HID);                                    \
    pal3 = *(const uint4*)(ApL_ + 96 * HID);                                    \
    pbh0 = *(const uint4*)(BpH_);                                               \
    pbh1 = *(const uint4*)(BpH_ + (size_t)32 * (2 * KTOT));                     \
    pbl0 = *(const uint4*)(BpL_);                                               \
    pbl1 = *(const uint4*)(BpL_ + (size_t)32 * (2 * KTOT));                     \
  }

// One 32-wide k-slice: 12 frag reads -> 24 MFMAs (pass-fused hi*hi + lo*hi + hi*lo).
#define MFMA_(A, B, C) C = __builtin_amdgcn_mfma_f32_16x16x32_bf16(A, B, C, 0, 0, 0)
#define KKBODY(KKC)                                                             \
  {                                                                             \
    const int so_ = sl0 ^ ((KKC) ? 64 : 0);                                     \
    const bf16x8 ah0_ = *(const bf16x8*)(Asb + arow +     0 + so_);             \
    const bf16x8 ah1_ = *(const bf16x8*)(Asb + arow +  4096 + so_);             \
    const bf16x8 ah2_ = *(const bf16x8*)(Asb + arow +  8192 + so_);             \
    const bf16x8 ah3_ = *(const bf16x8*)(Asb + arow + 12288 + so_);             \
    const bf16x8 bh0_ = *(const bf16x8*)(Bsb + brow +     0 + so_);             \
    const bf16x8 bh1_ = *(const bf16x8*)(Bsb + brow +  4096 + so_);             \
    MFMA_(bh0_, ah0_, acc00); MFMA_(bh0_, ah1_, acc01);                         \
    MFMA_(bh0_, ah2_, acc02); MFMA_(bh0_, ah3_, acc03);                         \
    MFMA_(bh1_, ah0_, acc10); MFMA_(bh1_, ah1_, acc11);                         \
    MFMA_(bh1_, ah2_, acc12); MFMA_(bh1_, ah3_, acc13);                         \
    const bf16x8 bl0_ = *(const bf16x8*)(Bsb + brow +     0 + (so_ ^ 128));     \
    const bf16x8 bl1_ = *(const bf16x8*)(Bsb + brow +  4096 + (so_ ^ 128));     \
    MFMA_(bl0_, ah0_, acc00); MFMA_(bl0_, ah1_, acc01);                         \
    MFMA_(bl0_, ah2_, acc02); MFMA_(bl0_, ah3_, acc03);                         \
    MFMA_(bl1_, ah0_, acc10); MFMA_(bl1_, ah1_, acc11);                         \
    MFMA_(bl1_, ah2_, acc12); MFMA_(bl1_, ah3_, acc13);                         \
    const bf16x8 al0_ = *(const bf16x8*)(Asb + arow +     0 + (so_ ^ 128));     \
    const bf16x8 al1_ = *(const bf16x8*)(Asb + arow +  4096 + (so_ ^ 128));     \
    const bf16x8 al2_ = *(const bf16x8*)(Asb + arow +  8192 + (so_ ^ 128));     \
    const bf16x8 al3_ = *(const bf16x8*)(Asb + arow + 12288 + (so_ ^ 128));     \
    MFMA_(bh0_, al0_, acc00); MFMA_(bh0_, al1_, acc01);                         \
    MFMA_(bh0_, al2_, acc02); MFMA_(bh0_, al3_, acc03);                         \
    MFMA_(bh1_, al0_, acc10); MFMA_(bh1_, al1_, acc11);                         \
    MFMA_(bh1_, al2_, acc12); MFMA_(bh1_, al3_, acc13);                         \
  }

#define EPI(I, J, ACC)                                                          \
  {                                                                             \
    const int hg_ = hg0 + wn * 8 + (I) * 4 + lq;                                \
    const int ml_ = wm * 64 + (J) * 16 + l15;                                   \
    const int mg_ = mg0 + ml_;                                                  \
    const float4 b4_ = *(const float4*)(bias + 4 * hg_);                        \
    float g0_ = ACC[0] + b4_.x, g1_ = ACC[1] + b4_.y;                           \
    float g2_ = ACC[2] + b4_.z, g3_ = ACC[3] + b4_.w;                           \
    if (HASX) {                                                                 \
      const float x0_ = xptr[(size_t)mg_ * xstride + 0];                        \
      const float x1_ = xptr[(size_t)mg_ * xstride + 1];                        \
      const float4 wA_ = *(const float4*)(wih + 8 * hg_);                       \
      const float4 wB_ = *(const float4*)(wih + 8 * hg_ + 4);                   \
      g0_ += x0_ * wA_.x + x1_ * wA_.y;  g1_ += x0_ * wA_.z + x1_ * wA_.w;      \
      g2_ += x0_ * wB_.x + x1_ * wB_.y;  g3_ += x0_ * wB_.z + x1_ * wB_.w;      \
    }                                                                           \
    const float ig_ = sigm(g0_), fg_ = sigm(g1_);                               \
    const float gg_ = tanh_fast(g2_), og_ = sigm(g3_);                          \
    float* cp_ = CstT + (size_t)hg_ * BATCH + mg_;                              \
    const float cn_ = fg_ * (*cp_) + ig_ * gg_;                                 \
    *cp_ = cn_;                                                                 \
    const float hn_ = og_ * tanh_fast(cn_);                                     \
    const u16 hi_ = f2bf(hn_);                                                  \
    Hsh[ml_ * 17 + wn * 8 + (I) * 4 + lq] = hi_;                                \
    Hsl[ml_ * 17 + wn * 8 + (I) * 4 + lq] = f2bf(hn_ - bf2f(hi_));              \
    if (PROJ) { s0##J += hn_ * wl[hg_]; s1##J += hn_ * wl[HID + hg_]; }         \
  }

// BM=128, BN=64, BK=64, pass-fused. LDS: As[128 rows][256B] (hi|lo interleaved,
// XOR-16 swizzled) + Bs[64][256B] = 49152 B. Swapped MFMA: D[n][m] -> in-reg epilogue.
template <int KTOT, bool HASX, bool PROJ>
__device__ __forceinline__ void run_gemm(const GArgs& g, int mt, int nt, char* smem) {
  const u16* const Ah0 = g.Ah0;  const u16* const Ah1 = g.Ah1;
  const u16* const Al0 = g.Al0;  const u16* const Al1 = g.Al1;
  const u16* const Bt  = g.Bt;
  const float* const bias = g.bias;
  const float* const xptr = g.xptr; const int xstride = g.xstride;
  const float* const wih  = g.wih;
  float* const CstT = g.CstT;
  u16* const Hh = g.Hh;  u16* const Hl = g.Hl;
  const float* const wl = g.wl;
  float* const oacc = g.oacc;

  char* const Asb = smem;                    // 128 rows x 256B
  char* const Bsb = smem + 32768;            // 64 rows x 256B

  const int tid = threadIdx.x;
  const int wid = tid >> 6, lane = tid & 63;
  const int wm = wid >> 1, wn = wid & 1;     // 2x2 waves: wm->M half, wn->N half
  const int r0 = tid >> 3;                   // 0..31 staging row
  const int sl = tid & 7;                    // 16B slot (0..7)
  const int swb = ((sl ^ (r0 & 15)) << 4);   // swizzled store byte-col
  const int offA = r0 * 256 + swb;
  const int offB = r0 * 256 + swb;

  const int l15 = lane & 15, lq = lane >> 4;
  const int sl0 = ((lq ^ l15) & 15) << 4;    // kk=0 hi-read slot byte
  const int arow = (wm * 64 + l15) * 256;
  const int brow = (wn * 32 + l15) * 256;

  f32x4 acc00 = {}, acc01 = {}, acc02 = {}, acc03 = {};
  f32x4 acc10 = {}, acc11 = {}, acc12 = {}, acc13 = {};
  constexpr int TOT = KTOT / 64;

  uint4 pah0, pah1, pah2, pah3, pal0, pal1, pal2, pal3, pbh0, pbh1, pbl0, pbl1;
  LOADT(0);

  for (int ks = 0; ks < TOT; ++ks) {
    __syncthreads();                         // prev compute done, LDS free
    *(uint4*)(Asb + offA +     0)         = pah0;
    *(uint4*)(Asb + offA +  8192)         = pah1;
    *(uint4*)(Asb + offA + 16384)         = pah2;
    *(uint4*)(Asb + offA + 24576)         = pah3;
    *(uint4*)(Asb + (offA ^ 128) +     0) = pal0;
    *(uint4*)(Asb + (offA ^ 128) +  8192) = pal1;
    *(uint4*)(Asb + (offA ^ 128) + 16384) = pal2;
    *(uint4*)(Asb + (offA ^ 128) + 24576) = pal3;
    *(uint4*)(Bsb + offB)                 = pbh0;
    *(uint4*)(Bsb + offB + 8192)          = pbh1;
    *(uint4*)(Bsb + (offB ^ 128))         = pbl0;
    *(uint4*)(Bsb + (offB ^ 128) + 8192)  = pbl1;
    __syncthreads();                         // LDS ready
    if (ks + 1 < TOT) LOADT(ks + 1);         // prefetch hides under MFMA
    KKBODY(0);
    KKBODY(1);
  }

  // ---- in-register epilogue ----
  __syncthreads();                           // LDS reads done; reuse for H stage
  u16* const Hsh = (u16*)smem;               // [128][17]
  u16* const Hsl = Hsh + 128 * 17;

  const int mg0 = mt * 128, hg0 = nt * 16;
  float s00 = 0.f, s01 = 0.f, s02 = 0.f, s03 = 0.f;
  float s10 = 0.f, s11 = 0.f, s12 = 0.f, s13 = 0.f;

  EPI(0, 0, acc00); EPI(1, 0, acc10);
  EPI(0, 1, acc01); EPI(1, 1, acc11);
  EPI(0, 2, acc02); EPI(1, 2, acc12);
  EPI(0, 3, acc03); EPI(1, 3, acc13);

  if (PROJ) {                                // reduce over lq (this wave's 8 h)
    s00 += __shfl_xor(s00, 16); s00 += __shfl_xor(s00, 32);
    s01 += __shfl_xor(s01, 16); s01 += __shfl_xor(s01, 32);
    s02 += __shfl_xor(s02, 16); s02 += __shfl_xor(s02, 32);
    s03 += __shfl_xor(s03, 16); s03 += __shfl_xor(s03, 32);
    s10 += __shfl_xor(s10, 16); s10 += __shfl_xor(s10, 32);
    s11 += __shfl_xor(s11, 16); s11 += __shfl_xor(s11, 32);
    s12 += __shfl_xor(s12, 16); s12 += __shfl_xor(s12, 32);
    s13 += __shfl_xor(s13, 16); s13 += __shfl_xor(s13, 32);
    if (lq == 0) {
      float* o0 = oacc + (size_t)(mg0 + wm * 64 +  0 + l15) * OUTW;
      float* o1 = oacc + (size_t)(mg0 + wm * 64 + 16 + l15) * OUTW;
      float* o2 = oacc + (size_t)(mg0 + wm * 64 + 32 + l15) * OUTW;
      float* o3 = oacc + (size_t)(mg0 + wm * 64 + 48 + l15) * OUTW;
      unsafeAtomicAdd(o0 + 0, s00); unsafeAtomicAdd(o0 + 1, s10);
      unsafeAtomicAdd(o1 + 0, s01); unsafeAtomicAdd(o1 + 1, s11);
      unsafeAtomicAdd(o2 + 0, s02); unsafeAtomicAdd(o2 + 1, s12);
      unsafeAtomicAdd(o3 + 0, s03); unsafeAtomicAdd(o3 + 1, s13);
    }
  }

  __syncthreads();                           // H stage complete
#pragma unroll
  for (int q = 0; q < 8; ++q) {              // coalesced H writeback
    int m = (tid >> 4) + 16 * q, c = tid & 15;
    Hh[(size_t)(mg0 + m) * HID + hg0 + c] = Hsh[m * 17 + c];
    Hl[(size_t)(mg0 + m) * HID + hg0 + c] = Hsl[m * 17 + c];
  }
}

// XCD-pinned tile mapping: xcd = bid&7 always owns nt in [xcd*4, xcd*4+4)
template <int KTOT, bool HASX, bool PROJ>
__global__ __launch_bounds__(256, 2) void step_single(GArgs ga) {
  __shared__ __align__(16) char smem[49152];
  int bid = blockIdx.x;
  int xc = bid & 7, j = bid >> 3;            // j in [0,32)
  int nt = xc * 4 + (j & 3);
  int mt = j >> 2;
  run_gemm<KTOT, HASX, PROJ>(ga, mt, nt, smem);
}

// grid 512: q<32 -> L2(t) (+proj), q>=32 -> L1(t+1)  (independent GEMMs)
__global__ __launch_bounds__(256, 2) void step_fused(GArgs g2, GArgs g1) {
  __shared__ __align__(16) char smem[49152];
  int bid = blockIdx.x;
  int xc = bid & 7, q = bid >> 3;            // q in [0,64)
  int jj = q & 31;
  int nt = xc * 4 + (jj & 3);
  int mt = jj >> 2;
  if (q < 32) run_gemm<1024, false, true>(g2, mt, nt, smem);
  else        run_gemm<512, true, false>(g1, mt, nt, smem);
}

// ---------- host ----------
extern "C" void kernel_launch(void* const* d_in, const int* in_sizes, int n_in,
                              void* d_out, int out_size, void* d_ws, size_t ws_size,
                              hipStream_t stream) {
  const float* x    = (const float*)d_in[0];
  const float* Wih1 = (const float*)d_in[1];
  const float* Whh1 = (const float*)d_in[2];
  const float* b1   = (const float*)d_in[3];
  const float* Wih2 = (const float*)d_in[4];
  const float* Whh2 = (const float*)d_in[5];
  const float* b2   = (const float*)d_in[6];
  const float* Wl   = (const float*)d_in[7];
  const float* bl   = (const float*)d_in[8];
  float* out = (float*)d_out;
  (void)in_sizes; (void)n_in; (void)out_size; (void)ws_size;

  char* p = (char*)d_ws;
  auto alloc = [&](size_t bytes) -> char* {
    char* r = p; p += (bytes + 255) & ~(size_t)255; return r;
  };
  u16* Bt1 = (u16*)alloc((size_t)2048 * 1024 * 2);   // 4 MB
  u16* Bt2 = (u16*)alloc((size_t)2048 * 2048 * 2);   // 8 MB
  char* state0 = p;
  u16* Hb[8];                                        // H1h[2],H1l[2],H2h[2],H2l[2]
  for (int i = 0; i < 8; ++i) Hb[i] = (u16*)alloc((size_t)BATCH * HID * 2);
  float* C1 = (float*)alloc((size_t)BATCH * HID * 4);  // stored [512][1024]
  float* C2 = (float*)alloc((size_t)BATCH * HID * 4);
  size_t state_bytes = (size_t)(p - state0);
  float* b1p = (float*)alloc(2048 * 4);
  float* b2p = (float*)alloc(2048 * 4);
  float* w1p = (float*)alloc(2048 * 2 * 4);

  hipMemsetAsync(state0, 0, state_bytes, stream);    // h,c = 0
  init_out<<<(BATCH * OUTW + 255) / 256, 256, 0, stream>>>(bl, out);
  prep_bt1<<<8192, 256, 0, stream>>>(Whh1, Bt1);
  prep_bt2<<<16384, 256, 0, stream>>>(Wih2, Whh2, Bt2);
  prep_small<<<8, 256, 0, stream>>>(b1, b2, Wih1, b1p, b2p, w1p);

  auto mkL1 = [&](int t) -> GArgs {
    int par = t & 1, prev = par ^ 1;
    GArgs a{};
    a.Ah0 = Hb[0 + prev]; a.Ah1 = nullptr;
    a.Al0 = Hb[2 + prev]; a.Al1 = nullptr;
    a.Bt = Bt1; a.bias = b1p;
    a.xptr = (t < T_OBS) ? (x + 2 * t) : (out + 2 * (t - 1));
    a.xstride = (t < T_OBS) ? (2 * T_OBS) : OUTW;
    a.wih = w1p; a.CstT = C1;
    a.Hh = Hb[0 + par]; a.Hl = Hb[2 + par];
    a.wl = nullptr; a.oacc = nullptr;
    return a;
  };
  auto mkL2 = [&](int t) -> GArgs {
    int par = t & 1, prev = par ^ 1;
    GArgs a{};
    a.Ah0 = Hb[0 + par];  a.Ah1 = Hb[4 + prev];   // k<512: H1(t), k>=512: H2(t-1)
    a.Al0 = Hb[2 + par];  a.Al1 = Hb[6 + prev];
    a.Bt = Bt2; a.bias = b2p;
    a.xptr = nullptr; a.xstride = 0; a.wih = nullptr;
    a.CstT = C2;
    a.Hh = Hb[4 + par]; a.Hl = Hb[6 + par];
    a.wl = Wl; a.oacc = out + 2 * t;
    return a;
  };

  // step 0 layer 1
  step_single<512, true, false><<<256, 256, 0, stream>>>(mkL1(0));
  // observed steps: L2(t) and L1(t+1) are independent -> one 512-WG dispatch
  for (int t = 0; t < T_OBS - 1; ++t)
    step_fused<<<512, 256, 0, stream>>>(mkL2(t), mkL1(t + 1));
  // last observed L2 (writes out[63])
  step_single<1024, false, true><<<256, 256, 0, stream>>>(mkL2(T_OBS - 1));
  // future steps: strict chain L1 -> L2(+proj) -> L1 ...
  for (int t = T_OBS; t < NSTEPS; ++t) {
    step_single<512, true, false><<<256, 256, 0, stream>>>(mkL1(t));
    step_single<1024, false, true><<<256, 256, 0, stream>>>(mkL2(t));
  }
}